// Round 8
// baseline (1672.638 us; speedup 1.0000x reference)
//
#include <hip/hip_runtime.h>
#include <hip/hip_fp16.h>

#define N_VAR 256
#define M_CON 512
#define BATCH 64
#define SIGMA_C 1e-6f
#define RHO_C 0.1f
#define ALPHA_C 1.6f
#define NITERS 500

// ---------------------------------------------------------------------------
// K1: transpose A [512][256] -> At [256][512] per batch
// ---------------------------------------------------------------------------
__global__ __launch_bounds__(256) void k_transpose(const float* __restrict__ A,
                                                   float* __restrict__ At) {
  __shared__ float tile[32][33];
  int b = blockIdx.z;
  int n0 = blockIdx.x * 32;
  int m0 = blockIdx.y * 32;
  const float* Ab = A + (size_t)b * (M_CON * N_VAR);
  float* Atb = At + (size_t)b * (M_CON * N_VAR);
  int tx = threadIdx.x, ty = threadIdx.y;  // (32, 8)
#pragma unroll
  for (int j = 0; j < 32; j += 8)
    tile[ty + j][tx] = Ab[(size_t)(m0 + ty + j) * N_VAR + n0 + tx];
  __syncthreads();
#pragma unroll
  for (int j = 0; j < 32; j += 8)
    Atb[(size_t)(n0 + ty + j) * M_CON + m0 + tx] = tile[tx][ty + j];
}

// ---------------------------------------------------------------------------
// K2: batched NT GEMM  C[i][j] = alpha * sum_k X[i][k]*Y[j][k]  (+ diag)
// packC=1: write fp16-packed pairs in the ADMM block layout
// Gpk[s][j2][t2] with s=gi>>7, j2=(gj&127)>>1,
// t2=((gj>>7)*2+((gi&127)>>6))*64 + (gi&63). fp32 G never materializes.
// (Layout proven correct in rounds 6-7.)
// ---------------------------------------------------------------------------
__global__ __launch_bounds__(256) void k_ntgemm(
    const float* __restrict__ X, const float* __restrict__ Y,
    float* __restrict__ C, int I, int J, int K,
    long long bsX, long long bsY, long long bsC, float alpha,
    const float* __restrict__ diagv, int tilesJ, int packC) {
  int b = blockIdx.y;
  int ti = blockIdx.x / tilesJ, tj = blockIdx.x % tilesJ;
  int i0 = ti * 128, j0 = tj * 128;
  const float* Xb = X + (size_t)b * bsX;
  const float* Yb = Y + (size_t)b * bsY;
  float* Cb = C + (size_t)b * bsC;
  __shared__ float Xs[16][128];
  __shared__ float Ys[16][128];
  int tid = threadIdx.x;
  int tx = tid & 15, ty = tid >> 4;
  float acc[8][8];
#pragma unroll
  for (int r = 0; r < 8; ++r)
#pragma unroll
    for (int c = 0; c < 8; ++c) acc[r][c] = 0.0f;

  for (int kk = 0; kk < K; kk += 16) {
#pragma unroll
    for (int v = 0; v < 2; ++v) {
      int idx = v * 256 + tid;
      int row = idx >> 2;
      int k4 = (idx & 3) * 4;
      float4 gx = *(const float4*)(Xb + (size_t)(i0 + row) * K + kk + k4);
      Xs[k4 + 0][row] = gx.x; Xs[k4 + 1][row] = gx.y;
      Xs[k4 + 2][row] = gx.z; Xs[k4 + 3][row] = gx.w;
      float4 gy = *(const float4*)(Yb + (size_t)(j0 + row) * K + kk + k4);
      Ys[k4 + 0][row] = gy.x; Ys[k4 + 1][row] = gy.y;
      Ys[k4 + 2][row] = gy.z; Ys[k4 + 3][row] = gy.w;
    }
    __syncthreads();
#pragma unroll
    for (int k = 0; k < 16; ++k) {
      float xr[8], yr[8];
      *(float4*)&xr[0] = *(float4*)&Xs[k][ty * 8];
      *(float4*)&xr[4] = *(float4*)&Xs[k][ty * 8 + 4];
      *(float4*)&yr[0] = *(float4*)&Ys[k][tx * 8];
      *(float4*)&yr[4] = *(float4*)&Ys[k][tx * 8 + 4];
#pragma unroll
      for (int r = 0; r < 8; ++r)
#pragma unroll
        for (int c = 0; c < 8; ++c) acc[r][c] += xr[r] * yr[c];
    }
    __syncthreads();
  }
  if (packC) {
    unsigned* Cp = (unsigned*)Cb;  // per-batch: 4 slices x 32768 u32
#pragma unroll
    for (int r = 0; r < 8; ++r) {
      int gi = i0 + ty * 8 + r;
      int sl = gi >> 7, rl = gi & 127;
      int rh = rl >> 6, ll = rl & 63;
#pragma unroll
      for (int c = 0; c < 8; c += 2) {
        int gj = j0 + tx * 8 + c;
        int cg = gj >> 7, j2 = (gj & 127) >> 1;
        int t2 = ((((cg << 1) | rh) << 6) | ll);
        __half2 hh = __floats2half2_rn(acc[r][c] * alpha, acc[r][c + 1] * alpha);
        Cp[(size_t)sl * 32768 + j2 * 512 + t2] = *(unsigned*)&hh;
      }
    }
    return;
  }
#pragma unroll
  for (int r = 0; r < 8; ++r) {
    int gi = i0 + ty * 8 + r;
#pragma unroll
    for (int c = 0; c < 8; ++c) {
      int gj = j0 + tx * 8 + c;
      float val = acc[r][c] * alpha;
      if (diagv != nullptr && gi == gj) val += diagv[(size_t)b * N_VAR + gi] + SIGMA_C;
      Cb[(size_t)gi * J + gj] = val;
    }
  }
}

// ---------------------------------------------------------------------------
// K3: BLOCKED Gauss-Jordan inversion, NB=8 (SPD, no pivoting; Schur
// complements of an SPD matrix stay SPD -> stable).
// ---------------------------------------------------------------------------
__global__ __launch_bounds__(512, 2) void k_invert(const float* __restrict__ Mk,
                                                   float* __restrict__ Mi) {
  int b = blockIdx.x;
  const float* src = Mk + (size_t)b * 65536;
  float* dst = Mi + (size_t)b * 65536;
  int t = threadIdx.x;
  int c = t & 255, rh = t >> 8;

  float a[128];
#pragma unroll
  for (int j = 0; j < 128; ++j) a[j] = src[(size_t)(rh * 128 + j) * 256 + c];

  __shared__ float colPan[256][8];     // old pivot-column panel [row][f]
  __shared__ float rowPan[2][8][260];  // raw pivot-row panel [buf][e][c]
  __shared__ float PiSh[64];           // 8x8 pivot-block inverse (flat)
  __shared__ float Rp[8][260];         // scaled pivot-row panel R' [e][c]

  int rh_s = __builtin_amdgcn_readfirstlane(rh);        // wave-uniform
  int cw_s = __builtin_amdgcn_readfirstlane((t >> 6) & 3);  // c-quadrant of wave

  if (rh == 0) {
#pragma unroll
    for (int j = 0; j < 8; ++j) rowPan[0][j][c] = a[j];  // block 0 rows
  }
  __syncthreads();

  for (int s = 0; s < 32; ++s) {
    int kb = s * 8;
    int cur = s & 1, nxt = cur ^ 1;
    int kh = kb >> 7, kj = kb & 127;          // pivot rows: half kh, offset kj
    int khn = (kb + 8) >> 7, kjn = (kb + 8) & 127;
    bool mycol = (c >= kb) && (c < kb + 8);   // per-lane

    // Phase A: threads owning pivot columns dump OLD values (2 waves active)
    if (cw_s == (kb >> 6)) {
      if (mycol) {
        int f = c - kb;
#pragma unroll
        for (int j = 0; j < 128; ++j) colPan[rh * 128 + j][f] = a[j];
      }
    }
    // Phase B (overlapped): wave 0 inverts the 8x8 pivot block via shuffles
    if (t < 64) {
      int e = t >> 3, f = t & 7;
      float p = rowPan[cur][e][kb + f];
#pragma unroll
      for (int k2 = 0; k2 < 8; ++k2) {
        float piv = __shfl(p, k2 * 8 + k2);
        float rv = __shfl(p, k2 * 8 + f);
        float cv = __shfl(p, e * 8 + k2);
        float pivinv = 1.0f / piv;
        float srv = rv * pivinv;
        float gen = p - cv * srv;
        p = gen;
        if (e == k2) p = srv;
        if (f == k2) p = -cv * pivinv;
        if (e == k2 && f == k2) p = pivinv;
      }
      PiSh[t] = p;
    }
    __syncthreads();  // B_mid: colPan + PiSh ready (rowPan[cur] since B_top)

    // Phase C: rp[e] = R'[e][c] in registers; pivot cols carry Pi columns
    float rpan[8];
#pragma unroll
    for (int f2 = 0; f2 < 8; ++f2) rpan[f2] = rowPan[cur][f2][c];
    float rp[8];
#pragma unroll
    for (int e = 0; e < 8; ++e) {
      float4 p0 = *(const float4*)&PiSh[e * 8];      // broadcast
      float4 p1 = *(const float4*)&PiSh[e * 8 + 4];
      rp[e] = p0.x * rpan[0] + p0.y * rpan[1] + p0.z * rpan[2] + p0.w * rpan[3] +
              p1.x * rpan[4] + p1.y * rpan[5] + p1.z * rpan[6] + p1.w * rpan[7];
    }
    if (cw_s == (kb >> 6)) {
      if (mycol) {
        int f = c - kb;
#pragma unroll
        for (int e = 0; e < 8; ++e) rp[e] = PiSh[e * 8 + f];
      }
    }
#pragma unroll
    for (int e = 0; e < 8; ++e) Rp[e][c] = rp[e];  // both rh: same value, benign

    // Phase D: rank-8 update of all 128 owned elements
    bool myhalfk = (rh_s == kh);
    bool stashw = (s != 31) && (rh_s == khn);
#pragma unroll
    for (int j = 0; j < 128; ++j) {
      float4 c0 = *(const float4*)&colPan[rh * 128 + j][0];  // broadcast
      float4 c1 = *(const float4*)&colPan[rh * 128 + j][4];
      float aold = a[j];
      float nv = aold -
                 (c0.x * rp[0] + c0.y * rp[1] + c0.z * rp[2] + c0.w * rp[3] +
                  c1.x * rp[4] + c1.y * rp[5] + c1.z * rp[6] + c1.w * rp[7]);
      if (mycol) nv -= aold;                       // pivot-col correction
      if (myhalfk && j >= kj && j < kj + 8)        // uniform scalar branch
        nv = Rp[j - kj][c];                        // pivot-row override
      a[j] = nv;
      if (stashw && j >= kjn && j < kjn + 8)       // uniform scalar branch
        rowPan[nxt][j - kjn][c] = nv;              // stash next pivot rows
    }
    __syncthreads();  // B_top: stash/colPan/Rp consumption complete
  }

#pragma unroll
  for (int j = 0; j < 128; ++j) dst[(size_t)(rh * 128 + j) * 256 + c] = a[j];
}

// ---------------------------------------------------------------------------
// K4a: h = Minv * q  (column access via symmetry)
// ---------------------------------------------------------------------------
__global__ __launch_bounds__(256) void k_matvec_h(const float* __restrict__ Mi,
                                                  const float* __restrict__ q,
                                                  float* __restrict__ h) {
  int b = blockIdx.x, t = threadIdx.x;
  __shared__ float qs[256];
  qs[t] = q[(size_t)b * 256 + t];
  __syncthreads();
  const float* Mb = Mi + (size_t)b * 65536;
  float acc = 0.0f;
  for (int k = 0; k < 256; ++k) acc += Mb[(size_t)k * 256 + t] * qs[k];
  h[(size_t)b * 256 + t] = acc;
}

// K4b: d = A * h  via At columns
__global__ __launch_bounds__(512) void k_matvec_d(const float* __restrict__ At,
                                                  const float* __restrict__ h,
                                                  float* __restrict__ d) {
  int b = blockIdx.x, t = threadIdx.x;
  __shared__ float hs[256];
  if (t < 256) hs[t] = h[(size_t)b * 256 + t];
  __syncthreads();
  const float* Ab = At + (size_t)b * 131072;
  float acc = 0.0f;
  for (int n = 0; n < 256; ++n) acc += Ab[(size_t)n * 512 + t] * hs[n];
  d[(size_t)b * 512 + t] = acc;
}

// ---------------------------------------------------------------------------
// K6: ADMM loop — round-14: 1024-thread blocks, 32 G-words/thread.
// Round-7 post-mortem: halving G bytes (fp32->fp16) bought only 6% ->
// NOT BW-bound; the iteration is a ~3200cy fixed issue+latency chain
// (2 waves/SIMD x ~280 VALU inst + poll RT + exposed load latency + barrier).
// Fix the root cause of rounds 3/4's lost RA fight: shrink per-thread G to
// 32 words (1 row x 64 cols per thread). At launch_bounds(1024,4) the RA
// budget is 128 VGPRs; 32 live G + ~30 misc fits -> LICM keeps G resident,
// loads leave the loop. 4 waves/SIMD doubles latency overlap. FMA written
// as fma(fpext(f16), f32, f32) to fuse into v_fma_mix_f32 (kills the 128
// standalone cvts); 4 accumulators break the fma chain.
// Mapping: wv=t>>6, l=t&63; cg=wv&7 (64-col window), rh=wv>>3 (row half);
// row=rh*64+l; gsrc = base + (cg&1)*32*512 + (cg>>1)*128 + rh*64 + l,
// word k at k*512 <-> cols cg*64+2k,2k+1 <-> wbuf[wv][2k,2k+1].
// Protocol (tags, parity, 1 barrier/iter, update on t<128) unchanged.
// VALIDATION: FETCH_SIZE must drop sharply (G fetched once); VGPR <= 128.
// ---------------------------------------------------------------------------
__global__ __launch_bounds__(1024, 4) void k_admm4(
    const unsigned* __restrict__ Gpk_g, const float* __restrict__ dvec,
    const float* __restrict__ lv, const float* __restrict__ uv,
    unsigned long long* __restrict__ wtag, float* __restrict__ Sbuf) {
  int g = blockIdx.x;
  int b = (g & 7) + 8 * ((g >> 3) & 7);
  int s = g >> 6;
  int t = threadIdx.x;
  int l = t & 63, wv = t >> 6;
  int cg = wv & 7, rh = wv >> 3;
  int c0 = cg * 64;

  __shared__ __align__(16) float wbuf[16][64];  // wave-private w windows
  __shared__ float part[2][8][128];             // parity double-buffered partials

  // Register-resident G: 32 packed fp16 pairs (this thread's row x 64 cols)
  const unsigned* gsrc = Gpk_g + (size_t)(b * 4 + s) * 32768 +
                         (size_t)((cg & 1) * 32) * 512 + (cg >> 1) * 128 +
                         rh * 64 + l;
  unsigned Gw[32];
#pragma unroll
  for (int k = 0; k < 32; ++k) Gw[k] = gsrc[(size_t)k * 512];

  int row_local = rh * 64 + l;  // this thread's partial-row
  float zreg = 0.0f, yreg = 0.0f, Sreg = 0.0f;
  float lreg = 0.0f, ureg = 0.0f, dreg = 0.0f;
  if (t < 128) {
    lreg = lv[(size_t)b * 512 + s * 128 + t];
    ureg = uv[(size_t)b * 512 + s * 128 + t];
    dreg = dvec[(size_t)b * 512 + s * 128 + t];
  }
  wbuf[wv][l] = 0.0f;  // w_0 = 0

  unsigned long long* wt0 = wtag + (size_t)b * 512;
  unsigned long long* wt1 = wtag + 32768 + (size_t)b * 512;
  const float* wrow = wbuf[wv];

  for (int it = 0; it < NITERS; ++it) {
    if (it > 0) {
      // latched poll of this wave's 64-col window: tag == it, buffer (it&1)
      unsigned long long* wp = (it & 1) ? wt1 : wt0;
      unsigned want = (unsigned)it;
      unsigned long long v = __hip_atomic_load(&wp[c0 + l], __ATOMIC_RELAXED,
                                               __HIP_MEMORY_SCOPE_AGENT);
      bool got = ((unsigned)(v >> 32) == want);
      while (!__all(got)) {
        if (!got) {
          unsigned long long v2 = __hip_atomic_load(
              &wp[c0 + l], __ATOMIC_RELAXED, __HIP_MEMORY_SCOPE_AGENT);
          if ((unsigned)(v2 >> 32) == want) { v = v2; got = true; }
        }
      }
      wbuf[wv][l] = __uint_as_float((unsigned)(v & 0xffffffffu));
      // same-wave ds_write -> ds_read: in-order, compiler inserts lgkmcnt
    }

    float a0 = 0.f, a1 = 0.f, a2 = 0.f, a3 = 0.f;
#pragma unroll
    for (int k = 0; k < 32; k += 4) {
      float4 w0 = *(const float4*)&wrow[2 * k];
      float4 w1 = *(const float4*)&wrow[2 * k + 4];
      __half2 h0 = *(__half2*)&Gw[k];
      __half2 h1 = *(__half2*)&Gw[k + 1];
      __half2 h2 = *(__half2*)&Gw[k + 2];
      __half2 h3 = *(__half2*)&Gw[k + 3];
      a0 = fmaf(__half2float(__low2half(h0)), w0.x, a0);
      a1 = fmaf(__half2float(__high2half(h0)), w0.y, a1);
      a2 = fmaf(__half2float(__low2half(h1)), w0.z, a2);
      a3 = fmaf(__half2float(__high2half(h1)), w0.w, a3);
      a0 = fmaf(__half2float(__low2half(h2)), w1.x, a0);
      a1 = fmaf(__half2float(__high2half(h2)), w1.y, a1);
      a2 = fmaf(__half2float(__low2half(h3)), w1.z, a2);
      a3 = fmaf(__half2float(__high2half(h3)), w1.w, a3);
    }
    int pp = it & 1;
    part[pp][cg][row_local] = (a0 + a1) + (a2 + a3);
    __syncthreads();  // the ONLY barrier: partials of iter `it` visible

    if (t < 128) {
      float w_old = RHO_C * zreg - yreg;
      Sreg = w_old - 0.6f * Sreg;
      float p = part[pp][0][t] + part[pp][1][t] + part[pp][2][t] +
                part[pp][3][t] + part[pp][4][t] + part[pp][5][t] +
                part[pp][6][t] + part[pp][7][t];
      float zt = p - dreg;
      float zh = ALPHA_C * zt + (1.0f - ALPHA_C) * zreg;
      float zc = zh + yreg * (1.0f / RHO_C);
      zc = fminf(fmaxf(zc, lreg), ureg);
      yreg += RHO_C * (zh - zc);
      zreg = zc;
      if (it < NITERS - 1) {
        float wn = RHO_C * zreg - yreg;
        unsigned long long pk =
            ((unsigned long long)(unsigned)(it + 1) << 32) |
            (unsigned long long)__float_as_uint(wn);
        unsigned long long* wp = ((it + 1) & 1) ? wt1 : wt0;
        __hip_atomic_store(&wp[s * 128 + t], pk, __ATOMIC_RELAXED,
                           __HIP_MEMORY_SCOPE_AGENT);
      }
    }
  }

  if (t < 128) Sbuf[(size_t)b * 512 + s * 128 + t] = Sreg;
}

// ---------------------------------------------------------------------------
// K7: epilogue  x = Minv * (alpha * A^T S - q)
// ---------------------------------------------------------------------------
__global__ __launch_bounds__(256) void k_final(
    const float* __restrict__ A, const float* __restrict__ q,
    const float* __restrict__ Mi, const float* __restrict__ Sbuf,
    float* __restrict__ xout) {
  int b = blockIdx.x, t = threadIdx.x;
  __shared__ float Ssh[512];
  __shared__ float uu[256];
  for (int i = t; i < 512; i += 256) Ssh[i] = Sbuf[(size_t)b * 512 + i];
  __syncthreads();
  const float* Ab = A + (size_t)b * 131072;
  float acc = 0.0f;
  for (int m = 0; m < 512; ++m) acc += Ab[(size_t)m * 256 + t] * Ssh[m];
  uu[t] = ALPHA_C * acc - q[(size_t)b * 256 + t];
  __syncthreads();
  const float* Mb = Mi + (size_t)b * 65536;
  float x = 0.0f;
  for (int kk = 0; kk < 256; ++kk) x += Mb[(size_t)kk * 256 + t] * uu[kk];
  xout[(size_t)b * 256 + t] = x;
}

// ---------------------------------------------------------------------------
extern "C" void kernel_launch(void* const* d_in, const int* in_sizes, int n_in,
                              void* d_out, int out_size, void* d_ws, size_t ws_size,
                              hipStream_t stream) {
  (void)in_sizes; (void)n_in; (void)out_size; (void)ws_size;
  const float* P = (const float*)d_in[0];
  const float* q = (const float*)d_in[1];
  const float* Av = (const float*)d_in[2];
  const float* lv = (const float*)d_in[3];
  const float* uv = (const float*)d_in[4];
  float* xout = (float*)d_out;

  float* ws = (float*)d_ws;
  float* At = ws;                       // 64*256*512; dies after k_matvec_d
  float* F  = ws;                       // alias of At; dies after ntgemm G
  float* Mi = ws + 8388608;             // 64*256*256
  float* Mk = ws + 12582912;            // dies after k_invert
  float* Gp = ws + 12582912;            // packed fp16 G: 64*131072 u32 = 32MB
  float* hv = ws + 29360128;            // 64*256
  float* dv = ws + 29376512;            // 64*512
  float* Sbuf = ws + 29409280;          // 64*512
  unsigned long long* wtag = (unsigned long long*)ws;  // overlays dead At/F
                                        // (F-GEMM rewrites the region each
                                        //  launch -> stale tags scrubbed)

  k_transpose<<<dim3(8, 16, 64), dim3(32, 8), 0, stream>>>(Av, At);
  k_ntgemm<<<dim3(4, 64), 256, 0, stream>>>(At, At, Mk, 256, 256, 512,
                                            131072LL, 131072LL, 65536LL,
                                            RHO_C, P, 2, 0);
  k_invert<<<64, 512, 0, stream>>>(Mk, Mi);
  k_matvec_h<<<64, 256, 0, stream>>>(Mi, q, hv);
  k_matvec_d<<<64, 512, 0, stream>>>(At, hv, dv);
  k_ntgemm<<<dim3(8, 64), 256, 0, stream>>>(Av, Mi, F, 512, 256, 256,
                                            131072LL, 65536LL, 131072LL,
                                            1.0f, nullptr, 2, 0);
  // G-GEMM writes packed fp16 directly (bsC in u32 units: 4*32768 per batch)
  k_ntgemm<<<dim3(16, 64), 256, 0, stream>>>(F, Av, Gp, 512, 512, 256,
                                             131072LL, 131072LL, 131072LL,
                                             1.0f, nullptr, 4, 1);
  k_admm4<<<256, 1024, 0, stream>>>((const unsigned*)Gp, dv, lv, uv, wtag, Sbuf);
  k_final<<<64, 256, 0, stream>>>(Av, q, Mi, Sbuf, xout);
}

// Round 9
// 1539.316 us; speedup vs baseline: 1.0866x; 1.0866x over previous
//
#include <hip/hip_runtime.h>
#include <hip/hip_fp16.h>

#define N_VAR 256
#define M_CON 512
#define BATCH 64
#define SIGMA_C 1e-6f
#define RHO_C 0.1f
#define ALPHA_C 1.6f
#define NITERS 500

typedef _Float16 f16x8 __attribute__((ext_vector_type(8)));
typedef float f32x4 __attribute__((ext_vector_type(4)));

// ---------------------------------------------------------------------------
// K1: transpose A [512][256] -> At [256][512] per batch
// ---------------------------------------------------------------------------
__global__ __launch_bounds__(256) void k_transpose(const float* __restrict__ A,
                                                   float* __restrict__ At) {
  __shared__ float tile[32][33];
  int b = blockIdx.z;
  int n0 = blockIdx.x * 32;
  int m0 = blockIdx.y * 32;
  const float* Ab = A + (size_t)b * (M_CON * N_VAR);
  float* Atb = At + (size_t)b * (M_CON * N_VAR);
  int tx = threadIdx.x, ty = threadIdx.y;  // (32, 8)
#pragma unroll
  for (int j = 0; j < 32; j += 8)
    tile[ty + j][tx] = Ab[(size_t)(m0 + ty + j) * N_VAR + n0 + tx];
  __syncthreads();
#pragma unroll
  for (int j = 0; j < 32; j += 8)
    Atb[(size_t)(n0 + ty + j) * M_CON + m0 + tx] = tile[tx][ty + j];
}

// ---------------------------------------------------------------------------
// K2: batched NT GEMM  C[i][j] = alpha * sum_k X[i][k]*Y[j][k]  (+ diag)
// packC=0: fp32 C.  packC=2: write split-fp16 C into Ch/Ce (row-major,
// J must be 256): ch = half(v), ce = half((v - float(ch)) * 256).
// ---------------------------------------------------------------------------
__global__ __launch_bounds__(256) void k_ntgemm(
    const float* __restrict__ X, const float* __restrict__ Y,
    float* __restrict__ C, float* __restrict__ C2, int I, int J, int K,
    long long bsX, long long bsY, long long bsC, float alpha,
    const float* __restrict__ diagv, int tilesJ, int packC) {
  int b = blockIdx.y;
  int ti = blockIdx.x / tilesJ, tj = blockIdx.x % tilesJ;
  int i0 = ti * 128, j0 = tj * 128;
  const float* Xb = X + (size_t)b * bsX;
  const float* Yb = Y + (size_t)b * bsY;
  __shared__ float Xs[16][128];
  __shared__ float Ys[16][128];
  int tid = threadIdx.x;
  int tx = tid & 15, ty = tid >> 4;
  float acc[8][8];
#pragma unroll
  for (int r = 0; r < 8; ++r)
#pragma unroll
    for (int c = 0; c < 8; ++c) acc[r][c] = 0.0f;

  for (int kk = 0; kk < K; kk += 16) {
#pragma unroll
    for (int v = 0; v < 2; ++v) {
      int idx = v * 256 + tid;
      int row = idx >> 2;
      int k4 = (idx & 3) * 4;
      float4 gx = *(const float4*)(Xb + (size_t)(i0 + row) * K + kk + k4);
      Xs[k4 + 0][row] = gx.x; Xs[k4 + 1][row] = gx.y;
      Xs[k4 + 2][row] = gx.z; Xs[k4 + 3][row] = gx.w;
      float4 gy = *(const float4*)(Yb + (size_t)(j0 + row) * K + kk + k4);
      Ys[k4 + 0][row] = gy.x; Ys[k4 + 1][row] = gy.y;
      Ys[k4 + 2][row] = gy.z; Ys[k4 + 3][row] = gy.w;
    }
    __syncthreads();
#pragma unroll
    for (int k = 0; k < 16; ++k) {
      float xr[8], yr[8];
      *(float4*)&xr[0] = *(float4*)&Xs[k][ty * 8];
      *(float4*)&xr[4] = *(float4*)&Xs[k][ty * 8 + 4];
      *(float4*)&yr[0] = *(float4*)&Ys[k][tx * 8];
      *(float4*)&yr[4] = *(float4*)&Ys[k][tx * 8 + 4];
#pragma unroll
      for (int r = 0; r < 8; ++r)
#pragma unroll
        for (int c = 0; c < 8; ++c) acc[r][c] += xr[r] * yr[c];
    }
    __syncthreads();
  }
  if (packC == 2) {
    unsigned* Ch = (unsigned*)C + (size_t)b * 65536;   // 512x256 halves
    unsigned* Ce = (unsigned*)C2 + (size_t)b * 65536;
#pragma unroll
    for (int r = 0; r < 8; ++r) {
      int gi = i0 + ty * 8 + r;
#pragma unroll
      for (int c = 0; c < 8; c += 2) {
        int gj = j0 + tx * 8 + c;
        float v0 = acc[r][c] * alpha, v1 = acc[r][c + 1] * alpha;
        __half2 hh = __floats2half2_rn(v0, v1);
        float2 fb = __half22float2(hh);
        __half2 he = __floats2half2_rn((v0 - fb.x) * 256.0f,
                                       (v1 - fb.y) * 256.0f);
        int idx = gi * 128 + (gj >> 1);
        Ch[idx] = *(unsigned*)&hh;
        Ce[idx] = *(unsigned*)&he;
      }
    }
    return;
  }
  float* Cb = C + (size_t)b * bsC;
#pragma unroll
  for (int r = 0; r < 8; ++r) {
    int gi = i0 + ty * 8 + r;
#pragma unroll
    for (int c = 0; c < 8; ++c) {
      int gj = j0 + tx * 8 + c;
      float val = acc[r][c] * alpha;
      if (diagv != nullptr && gi == gj) val += diagv[(size_t)b * N_VAR + gi] + SIGMA_C;
      Cb[(size_t)gi * J + gj] = val;
    }
  }
}

// ---------------------------------------------------------------------------
// K2b: split-fp16 cast of Av: ah = half(a), ae = half((a - float(ah))*256)
// ---------------------------------------------------------------------------
__global__ __launch_bounds__(256) void k_cast_split(
    const float* __restrict__ in, unsigned* __restrict__ oh,
    unsigned* __restrict__ oe, int n4) {
  int i = blockIdx.x * 256 + threadIdx.x;
  if (i >= n4) return;
  float4 v = ((const float4*)in)[i];
  __half2 h01 = __floats2half2_rn(v.x, v.y);
  __half2 h23 = __floats2half2_rn(v.z, v.w);
  float2 f01 = __half22float2(h01);
  float2 f23 = __half22float2(h23);
  __half2 e01 = __floats2half2_rn((v.x - f01.x) * 256.0f, (v.y - f01.y) * 256.0f);
  __half2 e23 = __floats2half2_rn((v.z - f23.x) * 256.0f, (v.w - f23.y) * 256.0f);
  uint2 uh; uh.x = *(unsigned*)&h01; uh.y = *(unsigned*)&h23;
  uint2 ue; ue.x = *(unsigned*)&e01; ue.y = *(unsigned*)&e23;
  ((uint2*)oh)[i] = uh;
  ((uint2*)oe)[i] = ue;
}

// ---------------------------------------------------------------------------
// K2c: G = F*A^T via MFMA f16 with split precision.
// G = Fh*Ah + (Fh*Ae + Fe*Ah)/256, fp32 accum -> numerically equals the
// fp32 product rounded once to fp16 (round-7 error profile).
// Fragment layout (CDNA 16x16x32_f16): A/B operand: lane l supplies
// row/col (l&15), k = (l>>4)*8 + i (8 contiguous fp16 = one 16B load).
// C/D: col = lane&15, row = (lane>>4)*4 + reg [HW-verified].
// Per wave: 32x32 output tile; block = 4 waves side-by-side in columns.
// Output written in the packed ADMM layout (pairs along gj via shfl_xor).
// ---------------------------------------------------------------------------
__global__ __launch_bounds__(256, 4) void k_mfma_g(
    const _Float16* __restrict__ Fh, const _Float16* __restrict__ Fe,
    const _Float16* __restrict__ Ah, const _Float16* __restrict__ Ae,
    unsigned* __restrict__ Gp) {
  int b = blockIdx.y;
  int bx = blockIdx.x;  // 64: ti = bx>>2 (16 row tiles), cj = bx&3
  int t = threadIdx.x, l = t & 63, wv = t >> 6;
  int i0 = (bx >> 2) * 32;
  int j0 = (bx & 3) * 128 + wv * 32;
  const _Float16* Fhb = Fh + (size_t)b * 131072;
  const _Float16* Feb = Fe + (size_t)b * 131072;
  const _Float16* Ahb = Ah + (size_t)b * 131072;
  const _Float16* Aeb = Ae + (size_t)b * 131072;
  unsigned* Gpb = Gp + (size_t)b * 131072;

  int lr = l & 15, lk = (l >> 4) * 8;
  f32x4 acc00 = {0,0,0,0}, acc01 = {0,0,0,0}, acc10 = {0,0,0,0}, acc11 = {0,0,0,0};
  f32x4 ar00 = {0,0,0,0}, ar01 = {0,0,0,0}, ar10 = {0,0,0,0}, ar11 = {0,0,0,0};

  for (int kk = 0; kk < 256; kk += 32) {
    f16x8 af0 = *(const f16x8*)&Fhb[(size_t)(i0 + lr) * 256 + kk + lk];
    f16x8 af1 = *(const f16x8*)&Fhb[(size_t)(i0 + 16 + lr) * 256 + kk + lk];
    f16x8 ae0 = *(const f16x8*)&Feb[(size_t)(i0 + lr) * 256 + kk + lk];
    f16x8 ae1 = *(const f16x8*)&Feb[(size_t)(i0 + 16 + lr) * 256 + kk + lk];
    f16x8 bf0 = *(const f16x8*)&Ahb[(size_t)(j0 + lr) * 256 + kk + lk];
    f16x8 bf1 = *(const f16x8*)&Ahb[(size_t)(j0 + 16 + lr) * 256 + kk + lk];
    f16x8 be0 = *(const f16x8*)&Aeb[(size_t)(j0 + lr) * 256 + kk + lk];
    f16x8 be1 = *(const f16x8*)&Aeb[(size_t)(j0 + 16 + lr) * 256 + kk + lk];
    acc00 = __builtin_amdgcn_mfma_f32_16x16x32_f16(af0, bf0, acc00, 0, 0, 0);
    acc01 = __builtin_amdgcn_mfma_f32_16x16x32_f16(af0, bf1, acc01, 0, 0, 0);
    acc10 = __builtin_amdgcn_mfma_f32_16x16x32_f16(af1, bf0, acc10, 0, 0, 0);
    acc11 = __builtin_amdgcn_mfma_f32_16x16x32_f16(af1, bf1, acc11, 0, 0, 0);
    ar00 = __builtin_amdgcn_mfma_f32_16x16x32_f16(af0, be0, ar00, 0, 0, 0);
    ar01 = __builtin_amdgcn_mfma_f32_16x16x32_f16(af0, be1, ar01, 0, 0, 0);
    ar10 = __builtin_amdgcn_mfma_f32_16x16x32_f16(af1, be0, ar10, 0, 0, 0);
    ar11 = __builtin_amdgcn_mfma_f32_16x16x32_f16(af1, be1, ar11, 0, 0, 0);
    ar00 = __builtin_amdgcn_mfma_f32_16x16x32_f16(ae0, bf0, ar00, 0, 0, 0);
    ar01 = __builtin_amdgcn_mfma_f32_16x16x32_f16(ae0, bf1, ar01, 0, 0, 0);
    ar10 = __builtin_amdgcn_mfma_f32_16x16x32_f16(ae1, bf0, ar10, 0, 0, 0);
    ar11 = __builtin_amdgcn_mfma_f32_16x16x32_f16(ae1, bf1, ar11, 0, 0, 0);
  }

#pragma unroll
  for (int tr = 0; tr < 2; ++tr)
#pragma unroll
    for (int tc = 0; tc < 2; ++tc) {
      const f32x4* am = (tr == 0) ? ((tc == 0) ? &acc00 : &acc01)
                                  : ((tc == 0) ? &acc10 : &acc11);
      const f32x4* ae = (tr == 0) ? ((tc == 0) ? &ar00 : &ar01)
                                  : ((tc == 0) ? &ar10 : &ar11);
#pragma unroll
      for (int r = 0; r < 4; ++r) {
        float v = (*am)[r] + (*ae)[r] * (1.0f / 256.0f);
        float vp = __shfl_xor(v, 1);
        int gi = i0 + tr * 16 + (l >> 4) * 4 + r;
        int gj = j0 + tc * 16 + lr;
        if (!(l & 1)) {
          __half2 hh = __floats2half2_rn(v, vp);
          int sl = gi >> 7, rl = gi & 127;
          int t2 = ((((gj >> 7) << 1) | (rl >> 6)) << 6) | (rl & 63);
          Gpb[(size_t)sl * 32768 + ((gj & 127) >> 1) * 512 + t2] = *(unsigned*)&hh;
        }
      }
    }
}

// ---------------------------------------------------------------------------
// K3: BLOCKED Gauss-Jordan inversion, NB=8 (SPD, no pivoting).
// ---------------------------------------------------------------------------
__global__ __launch_bounds__(512, 2) void k_invert(const float* __restrict__ Mk,
                                                   float* __restrict__ Mi) {
  int b = blockIdx.x;
  const float* src = Mk + (size_t)b * 65536;
  float* dst = Mi + (size_t)b * 65536;
  int t = threadIdx.x;
  int c = t & 255, rh = t >> 8;

  float a[128];
#pragma unroll
  for (int j = 0; j < 128; ++j) a[j] = src[(size_t)(rh * 128 + j) * 256 + c];

  __shared__ float colPan[256][8];
  __shared__ float rowPan[2][8][260];
  __shared__ float PiSh[64];
  __shared__ float Rp[8][260];

  int rh_s = __builtin_amdgcn_readfirstlane(rh);
  int cw_s = __builtin_amdgcn_readfirstlane((t >> 6) & 3);

  if (rh == 0) {
#pragma unroll
    for (int j = 0; j < 8; ++j) rowPan[0][j][c] = a[j];
  }
  __syncthreads();

  for (int s = 0; s < 32; ++s) {
    int kb = s * 8;
    int cur = s & 1, nxt = cur ^ 1;
    int kh = kb >> 7, kj = kb & 127;
    int khn = (kb + 8) >> 7, kjn = (kb + 8) & 127;
    bool mycol = (c >= kb) && (c < kb + 8);

    if (cw_s == (kb >> 6)) {
      if (mycol) {
        int f = c - kb;
#pragma unroll
        for (int j = 0; j < 128; ++j) colPan[rh * 128 + j][f] = a[j];
      }
    }
    if (t < 64) {
      int e = t >> 3, f = t & 7;
      float p = rowPan[cur][e][kb + f];
#pragma unroll
      for (int k2 = 0; k2 < 8; ++k2) {
        float piv = __shfl(p, k2 * 8 + k2);
        float rv = __shfl(p, k2 * 8 + f);
        float cv = __shfl(p, e * 8 + k2);
        float pivinv = 1.0f / piv;
        float srv = rv * pivinv;
        float gen = p - cv * srv;
        p = gen;
        if (e == k2) p = srv;
        if (f == k2) p = -cv * pivinv;
        if (e == k2 && f == k2) p = pivinv;
      }
      PiSh[t] = p;
    }
    __syncthreads();

    float rpan[8];
#pragma unroll
    for (int f2 = 0; f2 < 8; ++f2) rpan[f2] = rowPan[cur][f2][c];
    float rp[8];
#pragma unroll
    for (int e = 0; e < 8; ++e) {
      float4 p0 = *(const float4*)&PiSh[e * 8];
      float4 p1 = *(const float4*)&PiSh[e * 8 + 4];
      rp[e] = p0.x * rpan[0] + p0.y * rpan[1] + p0.z * rpan[2] + p0.w * rpan[3] +
              p1.x * rpan[4] + p1.y * rpan[5] + p1.z * rpan[6] + p1.w * rpan[7];
    }
    if (cw_s == (kb >> 6)) {
      if (mycol) {
        int f = c - kb;
#pragma unroll
        for (int e = 0; e < 8; ++e) rp[e] = PiSh[e * 8 + f];
      }
    }
#pragma unroll
    for (int e = 0; e < 8; ++e) Rp[e][c] = rp[e];

    bool myhalfk = (rh_s == kh);
    bool stashw = (s != 31) && (rh_s == khn);
#pragma unroll
    for (int j = 0; j < 128; ++j) {
      float4 c0 = *(const float4*)&colPan[rh * 128 + j][0];
      float4 c1 = *(const float4*)&colPan[rh * 128 + j][4];
      float aold = a[j];
      float nv = aold -
                 (c0.x * rp[0] + c0.y * rp[1] + c0.z * rp[2] + c0.w * rp[3] +
                  c1.x * rp[4] + c1.y * rp[5] + c1.z * rp[6] + c1.w * rp[7]);
      if (mycol) nv -= aold;
      if (myhalfk && j >= kj && j < kj + 8)
        nv = Rp[j - kj][c];
      a[j] = nv;
      if (stashw && j >= kjn && j < kjn + 8)
        rowPan[nxt][j - kjn][c] = nv;
    }
    __syncthreads();
  }

#pragma unroll
  for (int j = 0; j < 128; ++j) dst[(size_t)(rh * 128 + j) * 256 + c] = a[j];
}

// ---------------------------------------------------------------------------
// K4a: h = Minv * q
// ---------------------------------------------------------------------------
__global__ __launch_bounds__(256) void k_matvec_h(const float* __restrict__ Mi,
                                                  const float* __restrict__ q,
                                                  float* __restrict__ h) {
  int b = blockIdx.x, t = threadIdx.x;
  __shared__ float qs[256];
  qs[t] = q[(size_t)b * 256 + t];
  __syncthreads();
  const float* Mb = Mi + (size_t)b * 65536;
  float acc = 0.0f;
  for (int k = 0; k < 256; ++k) acc += Mb[(size_t)k * 256 + t] * qs[k];
  h[(size_t)b * 256 + t] = acc;
}

// K4b: d = A * h  via At columns
__global__ __launch_bounds__(512) void k_matvec_d(const float* __restrict__ At,
                                                  const float* __restrict__ h,
                                                  float* __restrict__ d) {
  int b = blockIdx.x, t = threadIdx.x;
  __shared__ float hs[256];
  if (t < 256) hs[t] = h[(size_t)b * 256 + t];
  __syncthreads();
  const float* Ab = At + (size_t)b * 131072;
  float acc = 0.0f;
  for (int n = 0; n < 256; ++n) acc += Ab[(size_t)n * 512 + t] * hs[n];
  d[(size_t)b * 512 + t] = acc;
}

// ---------------------------------------------------------------------------
// K6: ADMM loop — round-15: round-7 winner (706 us) + G loads issued BEFORE
// the poll loop so their L2 latency hides under the poll wait. No pins (a
// pin forces waitcnt before the poll, defeating the purpose); worst case
// the scheduler sinks the loads back = neutral.
// Exchange protocol/barrier/update byte-identical to rounds 1-7.
// wtag moved to workspace tail; scrubbed by hipMemsetAsync each launch.
// ---------------------------------------------------------------------------
__global__ __launch_bounds__(512) void k_admm4(
    const unsigned* __restrict__ Gpk_g, const float* __restrict__ dvec,
    const float* __restrict__ lv, const float* __restrict__ uv,
    unsigned long long* __restrict__ wtag, float* __restrict__ Sbuf) {
  int g = blockIdx.x;
  int b = (g & 7) + 8 * ((g >> 3) & 7);
  int s = g >> 6;
  int t = threadIdx.x;
  int l = t & 63, wv = t >> 6;
  int c0 = wv * 64;
  int cg = wv >> 1, hc = wv & 1;

  __shared__ __align__(16) float wbuf[8][64];
  __shared__ float part[2][8][128];

  const unsigned* gsrc =
      Gpk_g + (size_t)(b * 4 + s) * 32768 + (size_t)(hc * 32) * 512 + cg * 128 + l;

  float zreg = 0.0f, yreg = 0.0f, Sreg = 0.0f;
  float lreg = 0.0f, ureg = 0.0f, dreg = 0.0f;
  if (t < 128) {
    lreg = lv[(size_t)b * 512 + s * 128 + t];
    ureg = uv[(size_t)b * 512 + s * 128 + t];
    dreg = dvec[(size_t)b * 512 + s * 128 + t];
  }
  wbuf[wv][l] = 0.0f;  // w_0 = 0

  unsigned long long* wt0 = wtag + (size_t)b * 512;
  unsigned long long* wt1 = wtag + 32768 + (size_t)b * 512;
  const float4* wq4 = (const float4*)(wbuf[wv]);

  for (int it = 0; it < NITERS; ++it) {
    // Issue this iteration's G loads BEFORE polling: no dependence on w,
    // so their ~200-500cy L2 latency overlaps the poll wait.
    unsigned gva[32], gvb[32];
#pragma unroll
    for (int k = 0; k < 32; ++k) {
      gva[k] = gsrc[(size_t)k * 512];
      gvb[k] = gsrc[(size_t)k * 512 + 64];
    }

    if (it > 0) {
      unsigned long long* wp = (it & 1) ? wt1 : wt0;
      unsigned want = (unsigned)it;
      unsigned long long v = __hip_atomic_load(&wp[c0 + l], __ATOMIC_RELAXED,
                                               __HIP_MEMORY_SCOPE_AGENT);
      bool got = ((unsigned)(v >> 32) == want);
      while (!__all(got)) {
        if (!got) {
          unsigned long long v2 = __hip_atomic_load(
              &wp[c0 + l], __ATOMIC_RELAXED, __HIP_MEMORY_SCOPE_AGENT);
          if ((unsigned)(v2 >> 32) == want) { v = v2; got = true; }
        }
      }
      wbuf[wv][l] = __uint_as_float((unsigned)(v & 0xffffffffu));
    }

    float r0a = 0.f, r0b = 0.f, r1a = 0.f, r1b = 0.f;
#pragma unroll
    for (int j = 0; j < 8; ++j) {
      float4 wa = wq4[2 * j];
      float4 wc = wq4[2 * j + 1];
      float2 fa0 = __half22float2(*(__half2*)&gva[4 * j + 0]);
      float2 fa1 = __half22float2(*(__half2*)&gva[4 * j + 1]);
      float2 fa2 = __half22float2(*(__half2*)&gva[4 * j + 2]);
      float2 fa3 = __half22float2(*(__half2*)&gva[4 * j + 3]);
      float2 fb0 = __half22float2(*(__half2*)&gvb[4 * j + 0]);
      float2 fb1 = __half22float2(*(__half2*)&gvb[4 * j + 1]);
      float2 fb2 = __half22float2(*(__half2*)&gvb[4 * j + 2]);
      float2 fb3 = __half22float2(*(__half2*)&gvb[4 * j + 3]);
      r0a += fa0.x * wa.x + fa0.y * wa.y + fa1.x * wa.z + fa1.y * wa.w;
      r0b += fa2.x * wc.x + fa2.y * wc.y + fa3.x * wc.z + fa3.y * wc.w;
      r1a += fb0.x * wa.x + fb0.y * wa.y + fb1.x * wa.z + fb1.y * wa.w;
      r1b += fb2.x * wc.x + fb2.y * wc.y + fb3.x * wc.z + fb3.y * wc.w;
    }
    int pp = it & 1;
    part[pp][wv][l] = r0a + r0b;
    part[pp][wv][64 + l] = r1a + r1b;
    __syncthreads();  // the ONLY barrier

    if (t < 128) {
      float w_old = RHO_C * zreg - yreg;
      Sreg = w_old - 0.6f * Sreg;
      float p = part[pp][0][t] + part[pp][1][t] + part[pp][2][t] +
                part[pp][3][t] + part[pp][4][t] + part[pp][5][t] +
                part[pp][6][t] + part[pp][7][t];
      float zt = p - dreg;
      float zh = ALPHA_C * zt + (1.0f - ALPHA_C) * zreg;
      float zc = zh + yreg * (1.0f / RHO_C);
      zc = fminf(fmaxf(zc, lreg), ureg);
      yreg += RHO_C * (zh - zc);
      zreg = zc;
      if (it < NITERS - 1) {
        float wn = RHO_C * zreg - yreg;
        unsigned long long pk =
            ((unsigned long long)(unsigned)(it + 1) << 32) |
            (unsigned long long)__float_as_uint(wn);
        unsigned long long* wp = ((it + 1) & 1) ? wt1 : wt0;
        __hip_atomic_store(&wp[s * 128 + t], pk, __ATOMIC_RELAXED,
                           __HIP_MEMORY_SCOPE_AGENT);
      }
    }
  }

  if (t < 128) Sbuf[(size_t)b * 512 + s * 128 + t] = Sreg;
}

// ---------------------------------------------------------------------------
// K7: epilogue  x = Minv * (alpha * A^T S - q)
// ---------------------------------------------------------------------------
__global__ __launch_bounds__(256) void k_final(
    const float* __restrict__ A, const float* __restrict__ q,
    const float* __restrict__ Mi, const float* __restrict__ Sbuf,
    float* __restrict__ xout) {
  int b = blockIdx.x, t = threadIdx.x;
  __shared__ float Ssh[512];
  __shared__ float uu[256];
  for (int i = t; i < 512; i += 256) Ssh[i] = Sbuf[(size_t)b * 512 + i];
  __syncthreads();
  const float* Ab = A + (size_t)b * 131072;
  float acc = 0.0f;
  for (int m = 0; m < 512; ++m) acc += Ab[(size_t)m * 256 + t] * Ssh[m];
  uu[t] = ALPHA_C * acc - q[(size_t)b * 256 + t];
  __syncthreads();
  const float* Mb = Mi + (size_t)b * 65536;
  float x = 0.0f;
  for (int kk = 0; kk < 256; ++kk) x += Mb[(size_t)kk * 256 + t] * uu[kk];
  xout[(size_t)b * 256 + t] = x;
}

// ---------------------------------------------------------------------------
// Workspace layout (float-slot offsets):
//   At: [0, 8388608)            transpose; dead after k_matvec_d
//   Ah: [0, 4194304)            split-fp16 A (written AFTER matvec_d)
//   Ae: [4194304, 8388608)
//   Mi: [8388608, 12582912)     live to the end
//   Mk: [12582912, 16777216)    dead after k_invert
//   Gp: [12582912, 20971520)    packed fp16 G (overwrites dead Mk)
//   Fh: [20971520, 25165824)    split-fp16 F
//   Fe: [25165824, 29360128)
//   hv/dv/Sbuf: [29360128, 29442048)
//   wtag: [29442048, 29573120)  zeroed by hipMemsetAsync each launch
// ---------------------------------------------------------------------------
extern "C" void kernel_launch(void* const* d_in, const int* in_sizes, int n_in,
                              void* d_out, int out_size, void* d_ws, size_t ws_size,
                              hipStream_t stream) {
  (void)in_sizes; (void)n_in; (void)out_size; (void)ws_size;
  const float* P = (const float*)d_in[0];
  const float* q = (const float*)d_in[1];
  const float* Av = (const float*)d_in[2];
  const float* lv = (const float*)d_in[3];
  const float* uv = (const float*)d_in[4];
  float* xout = (float*)d_out;

  float* ws = (float*)d_ws;
  float* At = ws;
  unsigned* Ah = (unsigned*)ws;
  unsigned* Ae = (unsigned*)(ws + 4194304);
  float* Mi = ws + 8388608;
  float* Mk = ws + 12582912;
  float* Gp = ws + 12582912;
  float* Fh = ws + 20971520;
  float* Fe = ws + 25165824;
  float* hv = ws + 29360128;
  float* dv = ws + 29376512;
  float* Sbuf = ws + 29409280;
  unsigned long long* wtag = (unsigned long long*)(ws + 29442048);

  hipMemsetAsync(wtag, 0, 131072 * 4, stream);  // scrub stale tags (1 MB... 512KB? 65536 u64 x2 buffers = 131072 u64? No: 2x32768 u64 = 65536 u64 = 512KB; region is 131072 float-slots = 512KB. OK.)

  k_transpose<<<dim3(8, 16, 64), dim3(32, 8), 0, stream>>>(Av, At);
  k_ntgemm<<<dim3(4, 64), 256, 0, stream>>>(At, At, Mk, nullptr, 256, 256, 512,
                                            131072LL, 131072LL, 65536LL,
                                            RHO_C, P, 2, 0);
  k_invert<<<64, 512, 0, stream>>>(Mk, Mi);
  k_matvec_h<<<64, 256, 0, stream>>>(Mi, q, hv);
  k_matvec_d<<<64, 512, 0, stream>>>(At, hv, dv);
  // At is now dead: overwrite its region with split-fp16 A
  k_cast_split<<<8192, 256, 0, stream>>>(Av, Ah, Ae, 2097152);
  // F = Av * Mi  (fp32 compute, split-fp16 output)
  k_ntgemm<<<dim3(8, 64), 256, 0, stream>>>(Av, Mi, Fh, Fe, 512, 256, 256,
                                            131072LL, 65536LL, 0LL,
                                            1.0f, nullptr, 2, 2);
  // G = F * A^T  via MFMA, packed output
  k_mfma_g<<<dim3(64, 64), 256, 0, stream>>>(
      (const _Float16*)Fh, (const _Float16*)Fe,
      (const _Float16*)Ah, (const _Float16*)Ae, (unsigned*)Gp);
  k_admm4<<<256, 512, 0, stream>>>((const unsigned*)Gp, dv, lv, uv, wtag, Sbuf);
  k_final<<<64, 256, 0, stream>>>(Av, q, Mi, Sbuf, xout);
}